// Round 3
// baseline (95.978 us; speedup 1.0000x reference)
//
#include <hip/hip_runtime.h>

// Problem constants (match reference)
constexpr int Bv = 4;
constexpr int Cv = 1024;
constexpr int Hv = 64;
constexpr int Wv = 64;
constexpr int NROIS = 256;
constexpr int HWv = Hv * Wv;          // 4096
constexpr int PIX = Bv * HWv;         // 16384
constexpr int G = 32;                 // channel groups
constexpr int CPG = Cv / G;           // 32 channels per group

// ---------------------------------------------------------------------------
// k1: partial channel-summed squared diff. Thread t: g = t>>12 (channel
// group), v = t&4095 (float4 quad over pixels). 512 blocks x 256 threads.
// Reads the full 128 MiB input; BW-bound. Also zeroes out[0] (stream order
// guarantees this lands before k2's atomics).
// ---------------------------------------------------------------------------
__global__ __launch_bounds__(256) void k_diff2_partial(
    const float* __restrict__ std_f, const float* __restrict__ tch_f,
    float* __restrict__ partial, float* __restrict__ out) {
  if (blockIdx.x == 0 && threadIdx.x == 0) out[0] = 0.f;

  int t = blockIdx.x * 256 + threadIdx.x;  // [0, G*4096)
  int g = t >> 12;           // channel group
  int v = t & 4095;          // float4-unit index over all pixels
  int p = v << 2;            // pixel index, 4 consecutive
  int b = p >> 12;           // batch (HW = 4096)
  int hw = p & 4095;

  const float* ps = std_f + ((size_t)b * Cv + (size_t)g * CPG) * HWv + hw;
  const float* pt = tch_f + ((size_t)b * Cv + (size_t)g * CPG) * HWv + hw;

  float4 acc = make_float4(0.f, 0.f, 0.f, 0.f);
#pragma unroll 8
  for (int c = 0; c < CPG; ++c) {
    float4 s = *reinterpret_cast<const float4*>(ps + (size_t)c * HWv);
    float4 q = *reinterpret_cast<const float4*>(pt + (size_t)c * HWv);
    float dx = s.x - q.x, dy = s.y - q.y, dz = s.z - q.z, dw = s.w - q.w;
    acc.x += dx * dx;
    acc.y += dy * dy;
    acc.z += dz * dz;
    acc.w += dw * dw;
  }
  *reinterpret_cast<float4*>(partial + (size_t)g * PIX + p) = acc;
}

// ---------------------------------------------------------------------------
// block reduction helper (256 threads, wave64)
// ---------------------------------------------------------------------------
__device__ __forceinline__ float block_reduce_256(float v) {
  for (int off = 32; off > 0; off >>= 1) v += __shfl_down(v, off, 64);
  __shared__ float smem[4];
  int lane = threadIdx.x & 63;
  int wid = threadIdx.x >> 6;
  if (lane == 0) smem[wid] = v;
  __syncthreads();
  float r = 0.f;
  if (threadIdx.x == 0) r = smem[0] + smem[1] + smem[2] + smem[3];
  return r;
}

// ---------------------------------------------------------------------------
// k2: one block per ROI. Sums partial[g][rect] over all G groups (partial is
// 2 MB -> L2-resident), then atomicAdd of the ROI's mse/(B*N) into out[0].
// ---------------------------------------------------------------------------
__global__ __launch_bounds__(256) void k_roi_mse(
    const float* __restrict__ partial, const float* __restrict__ rois,
    const int* __restrict__ stride_p, float* __restrict__ out) {
  int roi_id = blockIdx.x;          // [0, 1024)
  int b = roi_id >> 8;
  const float* r = rois + (size_t)roi_id * 5;
  float inv_stride = 1.0f / (float)stride_p[0];

  int x1 = (int)floorf(r[1] * inv_stride);
  int y1 = (int)floorf(r[2] * inv_stride);
  int x2 = (int)floorf(r[3] * inv_stride);
  int y2 = (int)floorf(r[4] * inv_stride);

  if (!((y2 > y1) && (x2 > x1))) return;  // invalid ROI contributes 0

  int wroi = x2 - x1 + 1;
  int hroi = y2 - y1 + 1;
  int area = wroi * hroi;

  float acc = 0.f;
  const float* base = partial + (size_t)b * HWv;
#pragma unroll
  for (int g = 0; g < G; ++g) {
    const float* pg = base + (size_t)g * PIX;
    for (int idx = threadIdx.x; idx < area; idx += 256) {
      int yy = y1 + idx / wroi;
      int xx = x1 + idx % wroi;
      acc += pg[yy * Wv + xx];
    }
  }
  float sse = block_reduce_256(acc);
  if (threadIdx.x == 0) {
    float mse = sse / ((float)Cv * (float)area);
    atomicAdd(out, mse / (float)(Bv * NROIS));
  }
}

extern "C" void kernel_launch(void* const* d_in, const int* in_sizes, int n_in,
                              void* d_out, int out_size, void* d_ws,
                              size_t ws_size, hipStream_t stream) {
  const float* std_f = (const float*)d_in[0];
  const float* tch_f = (const float*)d_in[1];
  const float* rois = (const float*)d_in[2];
  const int* stride_p = (const int*)d_in[3];
  float* out = (float*)d_out;

  float* partial = (float*)d_ws;  // G*PIX floats = 2 MB

  k_diff2_partial<<<G * (PIX / 4) / 256, 256, 0, stream>>>(std_f, tch_f,
                                                           partial, out);
  k_roi_mse<<<Bv * NROIS, 256, 0, stream>>>(partial, rois, stride_p, out);
}

// Round 5
// 59.786 us; speedup vs baseline: 1.6054x; 1.6054x over previous
//
#include <hip/hip_runtime.h>

// Problem constants (match reference)
constexpr int Bv = 4;
constexpr int Cv = 1024;
constexpr int Hv = 64;
constexpr int Wv = 64;
constexpr int NROIS = 256;
constexpr int HWv = Hv * Wv;   // 4096
constexpr int PIX = Bv * HWv;  // 16384

// ---------------------------------------------------------------------------
// kA: block bid computes diff2 for 16 consecutive pixels (all 1024 channels,
// split as 64 channel-chunks x 4 pixel-quads across 256 threads). Writes
// 16 floats per block. Block 0 also zeroes out[0] (stream order => lands
// before kB's atomics).
// ---------------------------------------------------------------------------
__global__ __launch_bounds__(256, 4) void k_diff2(
    const float* __restrict__ std_f, const float* __restrict__ tch_f,
    float* __restrict__ diff2, float* __restrict__ out) {
  __shared__ float4 wsum[4][4];  // [wave][quad]

  const int tid = threadIdx.x;
  const int bid = blockIdx.x;
  if (bid == 0 && tid == 0) out[0] = 0.f;

  const int p0 = bid * 16;     // global pixel base
  const int b = p0 >> 12;      // batch (HW = 4096)
  const int hw = p0 & 4095;    // pixel within batch
  const int lane = tid & 63;
  const int w = tid >> 6;               // wave id [0,4)
  const int quad = lane & 3;            // pixel-quad [0,4)
  const int cc = w * 16 + (lane >> 2);  // channel chunk [0,64), 16 ch each

  const float* ps =
      std_f + ((size_t)b * Cv + (size_t)cc * 16) * HWv + hw + quad * 4;
  const float* pt =
      tch_f + ((size_t)b * Cv + (size_t)cc * 16) * HWv + hw + quad * 4;

  float4 acc = make_float4(0.f, 0.f, 0.f, 0.f);
#pragma unroll
  for (int c = 0; c < 16; ++c) {
    float4 s = *reinterpret_cast<const float4*>(ps + (size_t)c * HWv);
    float4 q = *reinterpret_cast<const float4*>(pt + (size_t)c * HWv);
    float dx = s.x - q.x, dy = s.y - q.y, dz = s.z - q.z, dw = s.w - q.w;
    acc.x += dx * dx;
    acc.y += dy * dy;
    acc.z += dz * dz;
    acc.w += dw * dw;
  }
  // reduce across the 16 channel-chunks within the wave (same quad every 4th lane)
#pragma unroll
  for (int off = 4; off < 64; off <<= 1) {
    acc.x += __shfl_down(acc.x, off, 64);
    acc.y += __shfl_down(acc.y, off, 64);
    acc.z += __shfl_down(acc.z, off, 64);
    acc.w += __shfl_down(acc.w, off, 64);
  }
  if (lane < 4) wsum[w][quad] = acc;
  __syncthreads();
  if (tid < 4) {  // tid = quad
    float4 a = wsum[0][tid], b4 = wsum[1][tid], c4 = wsum[2][tid],
           d4 = wsum[3][tid];
    float4 r;
    r.x = a.x + b4.x + c4.x + d4.x;
    r.y = a.y + b4.y + c4.y + d4.y;
    r.z = a.z + b4.z + c4.z + d4.z;
    r.w = a.w + b4.w + c4.w + d4.w;
    *reinterpret_cast<float4*>(diff2 + p0 + tid * 4) = r;
  }
}

// ---------------------------------------------------------------------------
// kB: one block per ROI; rectangle sum over diff2 (64 KB, cache-resident),
// atomicAdd of the normalized MSE into out[0].
// ---------------------------------------------------------------------------
__global__ __launch_bounds__(256) void k_roi_mse(
    const float* __restrict__ diff2, const float* __restrict__ rois,
    const int* __restrict__ stride_p, float* __restrict__ out) {
  __shared__ float rsum[4];
  const int tid = threadIdx.x;
  const int bid = blockIdx.x;
  const int lane = tid & 63;
  const int w = tid >> 6;

  const float* r = rois + (size_t)bid * 5;
  const float inv_stride = 1.0f / (float)stride_p[0];
  int x1 = (int)floorf(r[1] * inv_stride);
  int y1 = (int)floorf(r[2] * inv_stride);
  int x2 = (int)floorf(r[3] * inv_stride);
  int y2 = (int)floorf(r[4] * inv_stride);
  if (!((y2 > y1) && (x2 > x1))) return;  // invalid ROI contributes 0

  const int rb = bid >> 8;  // ROI's batch
  const float* d2 = diff2 + (size_t)rb * HWv;
  float a2 = 0.f;
  for (int yy = y1 + w; yy <= y2; yy += 4)        // rows across waves
    for (int xx = x1 + lane; xx <= x2; xx += 64)  // cols across lanes
      a2 += d2[yy * Wv + xx];
#pragma unroll
  for (int off = 32; off > 0; off >>= 1) a2 += __shfl_down(a2, off, 64);
  if (lane == 0) rsum[w] = a2;
  __syncthreads();
  if (tid == 0) {
    float sse = rsum[0] + rsum[1] + rsum[2] + rsum[3];
    int area = (y2 - y1 + 1) * (x2 - x1 + 1);
    float mse = sse / ((float)Cv * (float)area);
    atomicAdd(out, mse * (1.0f / (float)(Bv * NROIS)));
  }
}

extern "C" void kernel_launch(void* const* d_in, const int* in_sizes, int n_in,
                              void* d_out, int out_size, void* d_ws,
                              size_t ws_size, hipStream_t stream) {
  const float* std_f = (const float*)d_in[0];
  const float* tch_f = (const float*)d_in[1];
  const float* rois = (const float*)d_in[2];
  const int* stride_p = (const int*)d_in[3];
  float* out = (float*)d_out;
  float* diff2 = (float*)d_ws;  // PIX floats = 64 KB

  k_diff2<<<PIX / 16, 256, 0, stream>>>(std_f, tch_f, diff2, out);
  k_roi_mse<<<Bv * NROIS, 256, 0, stream>>>(diff2, rois, stride_p, out);
}

// Round 6
// 40.774 us; speedup vs baseline: 2.3539x; 1.4663x over previous
//
#include <hip/hip_runtime.h>

// Problem constants (match reference)
constexpr int Bv = 4;
constexpr int Cv = 1024;
constexpr int Hv = 64;
constexpr int Wv = 64;
constexpr int NROIS = 256;
constexpr int HWv = Hv * Wv;   // 4096
constexpr int PIX = Bv * HWv;  // 16384

// ---------------------------------------------------------------------------
// kA: block bid computes diff2 for 64 consecutive pixels over all 1024
// channels. 512 threads = 8 waves. Lane mapping: quad = lane&15 (which
// float4-quad of the 64 px), sub = lane>>4 (channel subgroup). Each wave
// covers 128 channels (4 subgroups x 32); each load instruction touches
// 4 contiguous 256 B segments -> full cache-line utilization.
// Reduction: shfl_xor over subgroups, LDS over waves. Writes 64 floats.
// Block 0 thread 0 zeroes out[0] (stream order => before kB's atomics).
// ---------------------------------------------------------------------------
__global__ __launch_bounds__(512) void k_diff2(
    const float* __restrict__ std_f, const float* __restrict__ tch_f,
    float* __restrict__ diff2, float* __restrict__ out) {
  __shared__ float4 wsum[8][16];  // [wave][quad]

  const int tid = threadIdx.x;
  const int bid = blockIdx.x;
  if (bid == 0 && tid == 0) out[0] = 0.f;

  const int p0 = bid * 64;     // block's pixel base (64 px, never straddles batch)
  const int b = p0 >> 12;      // batch (HW = 4096)
  const int hw = p0 & 4095;    // pixel within batch
  const int lane = tid & 63;
  const int w = tid >> 6;          // wave id [0,8)
  const int quad = lane & 15;      // float4-quad within 64 px
  const int sub = lane >> 4;       // channel subgroup [0,4)
  const int ch0 = w * 128 + sub * 32;  // first channel, 32 per thread

  const float* ps =
      std_f + ((size_t)b * Cv + ch0) * HWv + hw + quad * 4;
  const float* pt =
      tch_f + ((size_t)b * Cv + ch0) * HWv + hw + quad * 4;

  float4 acc = make_float4(0.f, 0.f, 0.f, 0.f);
#pragma unroll
  for (int c = 0; c < 32; ++c) {
    float4 s = *reinterpret_cast<const float4*>(ps + (size_t)c * HWv);
    float4 q = *reinterpret_cast<const float4*>(pt + (size_t)c * HWv);
    float dx = s.x - q.x, dy = s.y - q.y, dz = s.z - q.z, dw = s.w - q.w;
    acc.x += dx * dx;
    acc.y += dy * dy;
    acc.z += dz * dz;
    acc.w += dw * dw;
  }
  // sum the 4 channel subgroups (lanes q, q+16, q+32, q+48)
#pragma unroll
  for (int off = 16; off < 64; off <<= 1) {
    acc.x += __shfl_xor(acc.x, off, 64);
    acc.y += __shfl_xor(acc.y, off, 64);
    acc.z += __shfl_xor(acc.z, off, 64);
    acc.w += __shfl_xor(acc.w, off, 64);
  }
  if (lane < 16) wsum[w][lane] = acc;
  __syncthreads();
  if (tid < 16) {
    float4 r = make_float4(0.f, 0.f, 0.f, 0.f);
#pragma unroll
    for (int ww = 0; ww < 8; ++ww) {
      float4 a = wsum[ww][tid];
      r.x += a.x;
      r.y += a.y;
      r.z += a.z;
      r.w += a.w;
    }
    *reinterpret_cast<float4*>(diff2 + p0 + tid * 4) = r;
  }
}

// ---------------------------------------------------------------------------
// kB: one block per ROI; rectangle sum over diff2 (64 KB, cache-resident),
// atomicAdd of the normalized MSE into out[0].
// ---------------------------------------------------------------------------
__global__ __launch_bounds__(256) void k_roi_mse(
    const float* __restrict__ diff2, const float* __restrict__ rois,
    const int* __restrict__ stride_p, float* __restrict__ out) {
  __shared__ float rsum[4];
  const int tid = threadIdx.x;
  const int bid = blockIdx.x;
  const int lane = tid & 63;
  const int w = tid >> 6;

  const float* r = rois + (size_t)bid * 5;
  const float inv_stride = 1.0f / (float)stride_p[0];
  int x1 = (int)floorf(r[1] * inv_stride);
  int y1 = (int)floorf(r[2] * inv_stride);
  int x2 = (int)floorf(r[3] * inv_stride);
  int y2 = (int)floorf(r[4] * inv_stride);
  if (!((y2 > y1) && (x2 > x1))) return;  // invalid ROI contributes 0

  const int rb = bid >> 8;  // ROI's batch
  const float* d2 = diff2 + (size_t)rb * HWv;
  float a2 = 0.f;
  for (int yy = y1 + w; yy <= y2; yy += 4)        // rows across waves
    for (int xx = x1 + lane; xx <= x2; xx += 64)  // cols across lanes
      a2 += d2[yy * Wv + xx];
#pragma unroll
  for (int off = 32; off > 0; off >>= 1) a2 += __shfl_down(a2, off, 64);
  if (lane == 0) rsum[w] = a2;
  __syncthreads();
  if (tid == 0) {
    float sse = rsum[0] + rsum[1] + rsum[2] + rsum[3];
    int area = (y2 - y1 + 1) * (x2 - x1 + 1);
    float mse = sse / ((float)Cv * (float)area);
    atomicAdd(out, mse * (1.0f / (float)(Bv * NROIS)));
  }
}

extern "C" void kernel_launch(void* const* d_in, const int* in_sizes, int n_in,
                              void* d_out, int out_size, void* d_ws,
                              size_t ws_size, hipStream_t stream) {
  const float* std_f = (const float*)d_in[0];
  const float* tch_f = (const float*)d_in[1];
  const float* rois = (const float*)d_in[2];
  const int* stride_p = (const int*)d_in[3];
  float* out = (float*)d_out;
  float* diff2 = (float*)d_ws;  // PIX floats = 64 KB

  k_diff2<<<PIX / 64, 512, 0, stream>>>(std_f, tch_f, diff2, out);
  k_roi_mse<<<Bv * NROIS, 256, 0, stream>>>(diff2, rois, stride_p, out);
}